// Round 2
// baseline (924.601 us; speedup 1.0000x reference)
//
#include <hip/hip_runtime.h>
#include <hip/hip_bf16.h>
#include <math.h>

// Problem constants
#define BB      256
#define I_DIM   256
#define H_DIM   512
#define A_DIM   400
#define V_DIM   50000
#define OOV     50
#define VP      50050   // V + OOV
#define FC1_IN  912     // A + H
#define FC1_OUT 1024    // 2H
#define FC2_K   1024

typedef unsigned short u16;
typedef unsigned int   u32;
typedef __attribute__((ext_vector_type(8))) short  short8;
typedef __attribute__((ext_vector_type(4))) float  float4_;
typedef __attribute__((ext_vector_type(4))) u32    uint4_;

__device__ __forceinline__ u16 f2bf(float f) {
    u32 u = __builtin_bit_cast(u32, f);
    u32 r = (u + 0x7FFFu + ((u >> 16) & 1u)) >> 16;   // RNE
    return (u16)r;
}

#if __has_builtin(__builtin_amdgcn_cvt_pk_bf16_f32)
typedef __attribute__((ext_vector_type(2))) __bf16 bf16x2_t;
__device__ __forceinline__ u32 pk2bf(float lo, float hi) {
    bf16x2_t r = __builtin_amdgcn_cvt_pk_bf16_f32(lo, hi);
    return __builtin_bit_cast(u32, r);
}
#else
__device__ __forceinline__ u32 pk2bf(float lo, float hi) {
    return (u32)f2bf(lo) | ((u32)f2bf(hi) << 16);
}
#endif

// ---------------- Generic small fp32 GEMM: C[M,N] = A[M,K] @ W[N,K]^T ----------------
// 32x32 tile, BK=16, 256 threads, 2x2 micro-tile. N-guard only (M%32==0, K%16==0).
__global__ __launch_bounds__(256)
void sgemm32(const float* __restrict__ Am, const float* __restrict__ Wm,
             float* __restrict__ Cm, const float* __restrict__ bias0,
             const float* __restrict__ bias1, int M, int N, int K,
             int accumulate, int act)
{
    __shared__ float As[16][33];
    __shared__ float Bs[16][33];
    int t  = threadIdx.x;
    int tx = t & 15, ty = t >> 4;
    int m0 = blockIdx.y * 32, n0 = blockIdx.x * 32;
    int lm = t >> 3;           // 0..31
    int lk = (t & 7) * 2;      // 0..14
    const float* aptr = Am + (size_t)(m0 + lm) * K + lk;
    const float* wptr = Wm + (size_t)(n0 + lm) * K + lk;
    bool wvalid = (n0 + lm) < N;
    float c00 = 0.f, c01 = 0.f, c10 = 0.f, c11 = 0.f;

    for (int k0 = 0; k0 < K; k0 += 16) {
        float a0 = aptr[0], a1 = aptr[1];
        float w0 = wvalid ? wptr[0] : 0.f;
        float w1 = wvalid ? wptr[1] : 0.f;
        __syncthreads();
        As[lk][lm] = a0;  As[lk + 1][lm] = a1;
        Bs[lk][lm] = w0;  Bs[lk + 1][lm] = w1;
        __syncthreads();
#pragma unroll
        for (int k = 0; k < 16; ++k) {
            float av0 = As[k][ty], av1 = As[k][ty + 16];
            float bv0 = Bs[k][tx], bv1 = Bs[k][tx + 16];
            c00 += av0 * bv0;  c01 += av0 * bv1;
            c10 += av1 * bv0;  c11 += av1 * bv1;
        }
        aptr += 16; wptr += 16;
    }

    int r0 = m0 + ty, r1 = m0 + ty + 16;
    int cc0 = n0 + tx, cc1 = n0 + tx + 16;
    float accv[2][2] = {{c00, c01}, {c10, c11}};
    int rows[2] = {r0, r1};
    int cols[2] = {cc0, cc1};
#pragma unroll
    for (int i = 0; i < 2; ++i)
#pragma unroll
        for (int j = 0; j < 2; ++j) {
            int c = cols[j];
            if (c < N) {
                size_t idx = (size_t)rows[i] * N + c;
                float v = accv[i][j];
                if (accumulate) v += Cm[idx];
                if (bias0) v += bias0[c];
                if (bias1) v += bias1[c];
                if (act == 1) v = tanhf(v);
                Cm[idx] = v;
            }
        }
}

// ---------------- LSTM pointwise: c = sig(i)*tanh(g); h = sig(o)*tanh(c) ----------------
__global__ __launch_bounds__(256)
void lstm_h_kernel(const float* __restrict__ G, float* __restrict__ hbuf,
                   float* __restrict__ dec_in)
{
    int idx = blockIdx.x * 256 + threadIdx.x;     // 256*512
    int b = idx >> 9, j = idx & 511;
    const float* g = G + (size_t)b * 2048;
    float ig = g[j], gg = g[1024 + j], og = g[1536 + j];
    float si = 1.f / (1.f + expf(-ig));
    float so = 1.f / (1.f + expf(-og));
    float c  = si * tanhf(gg);
    float h  = so * tanhf(c);
    hbuf[idx] = h;
    dec_in[(size_t)b * FC1_IN + A_DIM + j] = h;
}

// ---------------- attention = v * softmax(e) per row ----------------
__global__ __launch_bounds__(256)
void att_kernel(const float* __restrict__ e, const float* __restrict__ vvec,
                float* __restrict__ att)
{
    __shared__ float s_ex[A_DIM];
    __shared__ float red[256];
    int b = blockIdx.x, t = threadIdx.x;
    const float* er = e + (size_t)b * A_DIM;
    float local = 0.f;
    for (int a = t; a < A_DIM; a += 256) {
        float ex = expf(er[a]);     // |e|<1 after tanh: no max-sub needed
        s_ex[a] = ex; local += ex;
    }
    red[t] = local; __syncthreads();
    for (int s = 128; s > 0; s >>= 1) {
        if (t < s) red[t] += red[t + s];
        __syncthreads();
    }
    float inv = 1.f / red[0];
    for (int a = t; a < A_DIM; a += 256)
        att[(size_t)b * A_DIM + a] = vvec[a] * s_ex[a] * inv;
}

// ---------------- context = att @ enc  (+ gen reduction) ----------------
__global__ __launch_bounds__(512)
void ctx_gen_kernel(const float* __restrict__ att, const float* __restrict__ enc,
                    const float* __restrict__ x, const float* __restrict__ h,
                    const float* __restrict__ pg1, const float* __restrict__ pg2,
                    const float* __restrict__ pg3,
                    float* __restrict__ dec_in, float* __restrict__ gen)
{
    __shared__ float s_att[A_DIM];
    __shared__ float red[512];
    int b = blockIdx.x, t = threadIdx.x;
    for (int a = t; a < A_DIM; a += 512) s_att[a] = att[(size_t)b * A_DIM + a];
    __syncthreads();
    float acc = 0.f;
    if (t < A_DIM) {
        const float* ep = enc + (size_t)b * (A_DIM * A_DIM) + t;
        float a0 = 0.f, a1 = 0.f, a2 = 0.f, a3 = 0.f;
#pragma unroll 2
        for (int a = 0; a < A_DIM; a += 4) {
            a0 += s_att[a]     * ep[(size_t)a * A_DIM];
            a1 += s_att[a + 1] * ep[(size_t)(a + 1) * A_DIM];
            a2 += s_att[a + 2] * ep[(size_t)(a + 2) * A_DIM];
            a3 += s_att[a + 3] * ep[(size_t)(a + 3) * A_DIM];
        }
        acc = (a0 + a1) + (a2 + a3);
        dec_in[(size_t)b * FC1_IN + t] = acc;
    }
    float local = 0.f;
    if (t < A_DIM) local += acc * pg2[t];
    if (t < I_DIM) local += x[(size_t)b * I_DIM + t] * pg1[t];
    local += h[(size_t)b * H_DIM + t] * pg3[t];     // t < 512 always
    red[t] = local; __syncthreads();
    for (int s = 256; s > 0; s >>= 1) {
        if (t < s) red[t] += red[t + s];
        __syncthreads();
    }
    if (t == 0) gen[b] = 1.f / (1.f + expf(-red[0]));
}

// ---------------- hid fp32 -> bf16 ----------------
__global__ __launch_bounds__(256)
void cvt_kernel(const float* __restrict__ hid, u16* __restrict__ hb)
{
    int idx = blockIdx.x * 256 + threadIdx.x;     // 256*1024
    hb[idx] = f2bf(hid[idx]);
}

// ---------------- fc2 via bf16 MFMA + exp + row-sum atomics ----------------
// Barrier-free, LDS-free. Block = 4 waves; wave tile = 64 rows x 32 cols.
// Block tile = 128 rows (blockIdx.y) x 64 cols (blockIdx.x).
// A (hb, bf16) read straight from global (L2-resident, 512 KB).
// W (fp32) read straight from global (L3-hot), converted in-register via
// packed cvt. No __syncthreads -> no vmcnt(0) drains; compiler pipelines.
__global__ __launch_bounds__(256)
void fc2_kernel(const u16* __restrict__ hb, const float* __restrict__ W,
                const float* __restrict__ bias, float* __restrict__ out,
                float* __restrict__ sums)
{
    int t = threadIdx.x;
    int wv = t >> 6, lane = t & 63;
    int lm = lane & 15, lk = lane >> 4;       // 0..15, 0..3
    int rh = wv & 1, ch = wv >> 1;
    int n0   = blockIdx.x * 64 + ch * 32;     // wave's 32-col base
    int row0 = blockIdx.y * 128 + rh * 64;    // wave's 64-row base

    float4_ acc[4][2];
#pragma unroll
    for (int mi = 0; mi < 4; ++mi)
#pragma unroll
        for (int ni = 0; ni < 2; ++ni)
            acc[mi][ni] = (float4_){0.f, 0.f, 0.f, 0.f};

    const u16* aptr = hb + (size_t)(row0 + lm) * FC2_K + lk * 8;
    int wr0 = n0 + lm;        if (wr0 > V_DIM - 1) wr0 = V_DIM - 1;
    int wr1 = n0 + 16 + lm;   if (wr1 > V_DIM - 1) wr1 = V_DIM - 1;
    const float* wp0 = W + (size_t)wr0 * FC2_K + lk * 8;
    const float* wp1 = W + (size_t)wr1 * FC2_K + lk * 8;

    for (int k0 = 0; k0 < FC2_K; k0 += 32) {
        short8 af[4];
#pragma unroll
        for (int mi = 0; mi < 4; ++mi)
            af[mi] = *(const short8*)(aptr + (size_t)mi * 16 * FC2_K + k0);
        float4_ w00 = *(const float4_*)(wp0 + k0);
        float4_ w01 = *(const float4_*)(wp0 + k0 + 4);
        float4_ w10 = *(const float4_*)(wp1 + k0);
        float4_ w11 = *(const float4_*)(wp1 + k0 + 4);

        uint4_ p0, p1;
        p0[0] = pk2bf(w00[0], w00[1]);  p0[1] = pk2bf(w00[2], w00[3]);
        p0[2] = pk2bf(w01[0], w01[1]);  p0[3] = pk2bf(w01[2], w01[3]);
        p1[0] = pk2bf(w10[0], w10[1]);  p1[1] = pk2bf(w10[2], w10[3]);
        p1[2] = pk2bf(w11[0], w11[1]);  p1[3] = pk2bf(w11[2], w11[3]);
        short8 bf0 = __builtin_bit_cast(short8, p0);
        short8 bf1 = __builtin_bit_cast(short8, p1);

#pragma unroll
        for (int mi = 0; mi < 4; ++mi)
            acc[mi][0] = __builtin_amdgcn_mfma_f32_16x16x32_bf16(af[mi], bf0,
                                                                 acc[mi][0], 0, 0, 0);
#pragma unroll
        for (int mi = 0; mi < 4; ++mi)
            acc[mi][1] = __builtin_amdgcn_mfma_f32_16x16x32_bf16(af[mi], bf1,
                                                                 acc[mi][1], 0, 0, 0);
    }

    // Epilogue: e = exp(acc + bias); store; row-sum via shfl + atomic.
#pragma unroll
    for (int mi = 0; mi < 4; ++mi) {
        int r_base = row0 + mi * 16 + lk * 4;   // rows r_base..r_base+3
        float s[4] = {0.f, 0.f, 0.f, 0.f};
#pragma unroll
        for (int ni = 0; ni < 2; ++ni) {
            int col = n0 + ni * 16 + lm;
            if (col < V_DIM) {
                float bcol = bias[col];
                float4_ a = acc[mi][ni];
#pragma unroll
                for (int r = 0; r < 4; ++r) {
                    float ev = expf(a[r] + bcol);
                    out[(size_t)(r_base + r) * VP + col] = ev;
                    s[r] += ev;
                }
            }
        }
#pragma unroll
        for (int off = 1; off < 16; off <<= 1) {
#pragma unroll
            for (int r = 0; r < 4; ++r) s[r] += __shfl_xor(s[r], off);
        }
        if (lm == 0) {
#pragma unroll
            for (int r = 0; r < 4; ++r) atomicAdd(&sums[r_base + r], s[r]);
        }
    }
}

// ---------------- out = gen/sum * exp ; zero OOV tail ----------------
__global__ __launch_bounds__(256)
void rescale_kernel(float* __restrict__ out, const float* __restrict__ gen,
                    const float* __restrict__ sums)
{
    int idx = (blockIdx.x * 256 + threadIdx.x) * 2;   // total 256*50050, even
    int b = idx / VP;
    int c = idx - b * VP;
    float2 v = *(float2*)(out + idx);
    float scale = gen[b] / sums[b];
    v.x = (c     < V_DIM) ? v.x * scale : 0.f;
    v.y = (c + 1 < V_DIM) ? v.y * scale : 0.f;
    *(float2*)(out + idx) = v;
}

// ---------------- scatter: out[b, ids[b,a]] += (1-gen[b]) * att[b,a] ----------------
__global__ __launch_bounds__(256)
void scatter_kernel(const int* __restrict__ ids, const float* __restrict__ att,
                    const float* __restrict__ gen, float* __restrict__ out)
{
    int idx = blockIdx.x * 256 + threadIdx.x;   // 256*400
    int b = idx / A_DIM;
    float val = (1.f - gen[b]) * att[idx];
    atomicAdd(out + (size_t)b * VP + ids[idx], val);
}

extern "C" void kernel_launch(void* const* d_in, const int* in_sizes, int n_in,
                              void* d_out, int out_size, void* d_ws, size_t ws_size,
                              hipStream_t stream)
{
    const float* x         = (const float*)d_in[0];
    const float* enc       = (const float*)d_in[2];
    const float* enc_state = (const float*)d_in[4];
    const int*   ids       = (const int*)  d_in[6];
    const float* W_ih      = (const float*)d_in[7];
    const float* b_ih      = (const float*)d_in[9];
    const float* b_hh      = (const float*)d_in[10];
    const float* Wh_w      = (const float*)d_in[11];
    const float* Wh_b      = (const float*)d_in[12];
    const float* Ws_w      = (const float*)d_in[13];
    const float* Ws_b      = (const float*)d_in[14];
    const float* vvec      = (const float*)d_in[15];
    const float* fc1_w     = (const float*)d_in[16];
    const float* fc1_b     = (const float*)d_in[17];
    const float* fc2_w     = (const float*)d_in[18];
    const float* fc2_b     = (const float*)d_in[19];
    const float* pg1       = (const float*)d_in[20];
    const float* pg2       = (const float*)d_in[21];
    const float* pg3       = (const float*)d_in[22];
    float* out = (float*)d_out;

    float* ws    = (float*)d_ws;
    float* gates = ws;                        // 256*2048
    float* hbuf  = gates + 256 * 2048;        // 256*512
    float* ebuf  = hbuf  + 256 * 512;         // 256*400
    float* attb  = ebuf  + 256 * 400;         // 256*400
    float* dec   = attb  + 256 * 400;         // 256*912
    float* hid   = dec   + 256 * 912;         // 256*1024
    float* genb  = hid   + 256 * 1024;        // 256
    float* sums  = genb  + 256;               // 256
    u16*   hbf   = (u16*)(sums + 256);        // 256*1024 bf16

    // zero row sums (early; fc2 is far downstream)
    hipMemsetAsync(sums, 0, BB * sizeof(float), stream);

    // gates = x0 @ W_ih^T + b_ih + b_hh
    sgemm32<<<dim3(64, 8), 256, 0, stream>>>(x, W_ih, gates, b_ih, b_hh,
                                             BB, 2048, I_DIM, 0, 0);
    // h
    lstm_h_kernel<<<512, 256, 0, stream>>>(gates, hbuf, dec);
    // e = tanh(ES@Wh^T + Wh_b + h@Ws^T + Ws_b)
    sgemm32<<<dim3(13, 8), 256, 0, stream>>>(enc_state, Wh_w, ebuf, Wh_b, nullptr,
                                             BB, A_DIM, H_DIM, 0, 0);
    sgemm32<<<dim3(13, 8), 256, 0, stream>>>(hbuf, Ws_w, ebuf, Ws_b, nullptr,
                                             BB, A_DIM, H_DIM, 1, 1);
    // attention
    att_kernel<<<BB, 256, 0, stream>>>(ebuf, vvec, attb);
    // context + gen
    ctx_gen_kernel<<<BB, 512, 0, stream>>>(attb, enc, x, hbuf, pg1, pg2, pg3,
                                           dec, genb);
    // fc1
    sgemm32<<<dim3(32, 8), 256, 0, stream>>>(dec, fc1_w, hid, fc1_b, nullptr,
                                             BB, FC1_OUT, FC1_IN, 0, 0);
    // hid -> bf16
    cvt_kernel<<<1024, 256, 0, stream>>>(hid, hbf);
    // fc2 + exp + row sums  (782 = ceil(50000/64), 2 row-blocks of 128)
    fc2_kernel<<<dim3(782, 2), 256, 0, stream>>>(hbf, fc2_w, fc2_b, out, sums);
    // scale by gen/sum, zero OOV tail
    rescale_kernel<<<(BB * VP) / 512, 256, 0, stream>>>(out, genb, sums);
    // pointer-copy scatter
    scatter_kernel<<<(BB * A_DIM) / 256, 256, 0, stream>>>(ids, attb, genb, out);
}

// Round 3
// 790.481 us; speedup vs baseline: 1.1697x; 1.1697x over previous
//
#include <hip/hip_runtime.h>
#include <hip/hip_bf16.h>
#include <math.h>

// Problem constants
#define BB      256
#define I_DIM   256
#define H_DIM   512
#define A_DIM   400
#define V_DIM   50000
#define OOV     50
#define VP      50050   // V + OOV
#define FC1_IN  912     // A + H
#define FC1_OUT 1024    // 2H
#define FC2_K   1024

typedef unsigned short u16;
typedef unsigned int   u32;
typedef __attribute__((ext_vector_type(8))) short  short8;
typedef __attribute__((ext_vector_type(4))) float  float4_;
typedef __attribute__((ext_vector_type(4))) u32    uint4_;

__device__ __forceinline__ u16 f2bf(float f) {
    u32 u = __builtin_bit_cast(u32, f);
    u32 r = (u + 0x7FFFu + ((u >> 16) & 1u)) >> 16;   // RNE
    return (u16)r;
}

#if __has_builtin(__builtin_amdgcn_cvt_pk_bf16_f32)
typedef __attribute__((ext_vector_type(2))) __bf16 bf16x2_t;
__device__ __forceinline__ u32 pk2bf(float lo, float hi) {
    bf16x2_t r = __builtin_amdgcn_cvt_pk_bf16_f32(lo, hi);
    return __builtin_bit_cast(u32, r);
}
#else
__device__ __forceinline__ u32 pk2bf(float lo, float hi) {
    return (u32)f2bf(lo) | ((u32)f2bf(hi) << 16);
}
#endif

// ---------------- fp32 GEMM: C[M,N] = A[M,K] @ W[N,K]^T ----------------
// 32x64 tile, BK=16, 256 threads, 2x4 micro-tile. Requires M%32==0, K%16==0,
// N%4==0 (N-guard per float4).
__global__ __launch_bounds__(256)
void sgemm(const float* __restrict__ Am, const float* __restrict__ Wm,
           float* __restrict__ Cm, const float* __restrict__ bias0,
           const float* __restrict__ bias1, int M, int N, int K,
           int accumulate, int act)
{
    __shared__ float As[16][36];
    __shared__ float Bs[16][68];
    int t  = threadIdx.x;
    int tx = t & 15, ty = t >> 4;
    int m0 = blockIdx.y * 32, n0 = blockIdx.x * 64;

    int ar = t >> 3;            // 0..31
    int ak = (t & 7) * 2;       // 0..14
    int br = t >> 2;            // 0..63
    int bk = (t & 3) * 4;       // 0,4,8,12
    const float* ap = Am + (size_t)(m0 + ar) * K + ak;
    int brow = n0 + br;
    const float* bp = Wm + (size_t)(brow < N ? brow : N - 1) * K + bk;

    float c_[2][4];
#pragma unroll
    for (int r = 0; r < 2; ++r)
#pragma unroll
        for (int i = 0; i < 4; ++i) c_[r][i] = 0.f;

    for (int k0 = 0; k0 < K; k0 += 16) {
        float2  av = *(const float2*)(ap + k0);
        float4_ bv = *(const float4_*)(bp + k0);
        __syncthreads();
        As[ak][ar] = av.x;  As[ak + 1][ar] = av.y;
        Bs[bk][br] = bv[0]; Bs[bk + 1][br] = bv[1];
        Bs[bk + 2][br] = bv[2]; Bs[bk + 3][br] = bv[3];
        __syncthreads();
#pragma unroll
        for (int k = 0; k < 16; ++k) {
            float a0 = As[k][ty * 2], a1 = As[k][ty * 2 + 1];
            float4_ b = *(const float4_*)&Bs[k][tx * 4];
#pragma unroll
            for (int i = 0; i < 4; ++i) {
                c_[0][i] += a0 * b[i];
                c_[1][i] += a1 * b[i];
            }
        }
    }

    int colb = n0 + tx * 4;
    if (colb < N) {
        float4_ b0v = bias0 ? *(const float4_*)(bias0 + colb) : (float4_){0,0,0,0};
        float4_ b1v = bias1 ? *(const float4_*)(bias1 + colb) : (float4_){0,0,0,0};
#pragma unroll
        for (int r = 0; r < 2; ++r) {
            int row = m0 + ty * 2 + r;
            float4_* cp = (float4_*)(Cm + (size_t)row * N + colb);
            float4_ v;
#pragma unroll
            for (int i = 0; i < 4; ++i) v[i] = c_[r][i] + b0v[i] + b1v[i];
            if (accumulate) {
                float4_ old = *cp;
#pragma unroll
                for (int i = 0; i < 4; ++i) v[i] += old[i];
            }
            if (act == 1) {
#pragma unroll
                for (int i = 0; i < 4; ++i) v[i] = tanhf(v[i]);
            }
            *cp = v;
        }
    }
}

// ---------------- LSTM pointwise: c = sig(i)*tanh(g); h = sig(o)*tanh(c) ----------------
__global__ __launch_bounds__(256)
void lstm_h_kernel(const float* __restrict__ G, float* __restrict__ hbuf,
                   float* __restrict__ dec_in)
{
    int idx = blockIdx.x * 256 + threadIdx.x;     // 256*512
    int b = idx >> 9, j = idx & 511;
    const float* g = G + (size_t)b * 2048;
    float ig = g[j], gg = g[1024 + j], og = g[1536 + j];
    float si = 1.f / (1.f + expf(-ig));
    float so = 1.f / (1.f + expf(-og));
    float c  = si * tanhf(gg);
    float h  = so * tanhf(c);
    hbuf[idx] = h;
    dec_in[(size_t)b * FC1_IN + A_DIM + j] = h;
}

// ---------------- attention = v * softmax(e) per row ----------------
__global__ __launch_bounds__(256)
void att_kernel(const float* __restrict__ e, const float* __restrict__ vvec,
                float* __restrict__ att)
{
    __shared__ float s_ex[A_DIM];
    __shared__ float red[256];
    int b = blockIdx.x, t = threadIdx.x;
    const float* er = e + (size_t)b * A_DIM;
    float local = 0.f;
    for (int a = t; a < A_DIM; a += 256) {
        float ex = expf(er[a]);     // |e|<1 after tanh: no max-sub needed
        s_ex[a] = ex; local += ex;
    }
    red[t] = local; __syncthreads();
    for (int s = 128; s > 0; s >>= 1) {
        if (t < s) red[t] += red[t + s];
        __syncthreads();
    }
    float inv = 1.f / red[0];
    for (int a = t; a < A_DIM; a += 256)
        att[(size_t)b * A_DIM + a] = vvec[a] * s_ex[a] * inv;
}

// ---------------- context = att @ enc  (+ gen reduction) ----------------
__global__ __launch_bounds__(512)
void ctx_gen_kernel(const float* __restrict__ att, const float* __restrict__ enc,
                    const float* __restrict__ x, const float* __restrict__ h,
                    const float* __restrict__ pg1, const float* __restrict__ pg2,
                    const float* __restrict__ pg3,
                    float* __restrict__ dec_in, float* __restrict__ gen)
{
    __shared__ float s_att[A_DIM];
    __shared__ float red[512];
    int b = blockIdx.x, t = threadIdx.x;
    for (int a = t; a < A_DIM; a += 512) s_att[a] = att[(size_t)b * A_DIM + a];
    __syncthreads();
    float acc = 0.f;
    if (t < A_DIM) {
        const float* ep = enc + (size_t)b * (A_DIM * A_DIM) + t;
        float s0 = 0.f, s1 = 0.f, s2 = 0.f, s3 = 0.f;
        float s4 = 0.f, s5 = 0.f, s6 = 0.f, s7 = 0.f;
        for (int a = 0; a < A_DIM; a += 8) {   // 400 = 8*50
            s0 += s_att[a]     * ep[(size_t)a * A_DIM];
            s1 += s_att[a + 1] * ep[(size_t)(a + 1) * A_DIM];
            s2 += s_att[a + 2] * ep[(size_t)(a + 2) * A_DIM];
            s3 += s_att[a + 3] * ep[(size_t)(a + 3) * A_DIM];
            s4 += s_att[a + 4] * ep[(size_t)(a + 4) * A_DIM];
            s5 += s_att[a + 5] * ep[(size_t)(a + 5) * A_DIM];
            s6 += s_att[a + 6] * ep[(size_t)(a + 6) * A_DIM];
            s7 += s_att[a + 7] * ep[(size_t)(a + 7) * A_DIM];
        }
        acc = ((s0 + s1) + (s2 + s3)) + ((s4 + s5) + (s6 + s7));
        dec_in[(size_t)b * FC1_IN + t] = acc;
    }
    float local = 0.f;
    if (t < A_DIM) local += acc * pg2[t];
    if (t < I_DIM) local += x[(size_t)b * I_DIM + t] * pg1[t];
    local += h[(size_t)b * H_DIM + t] * pg3[t];     // t < 512 always
    red[t] = local; __syncthreads();
    for (int s = 256; s > 0; s >>= 1) {
        if (t < s) red[t] += red[t + s];
        __syncthreads();
    }
    if (t == 0) gen[b] = 1.f / (1.f + expf(-red[0]));
}

// ---------------- hid fp32 -> bf16 ----------------
__global__ __launch_bounds__(256)
void cvt_kernel(const float* __restrict__ hid, u16* __restrict__ hb)
{
    int idx = blockIdx.x * 256 + threadIdx.x;     // 256*1024
    hb[idx] = f2bf(hid[idx]);
}

// ---------------- fc2 via bf16 MFMA, register-pipelined ----------------
// Block = 4 waves partitioning M (4 x 64 rows), sharing the SAME 32 W-rows
// (n0..n0+31) -> W streamed exactly once from HBM; intra-block re-reads hit
// L1/L2. Explicit ping-pong register double-buffer over 32-wide K-chunks
// forces loads of chunk c+1 in flight while MFMAs run on chunk c.
__device__ __forceinline__ void fc2_step(const short8* a, const float4_* w,
                                         float4_ acc[4][2])
{
    uint4_ p0, p1;
    p0[0] = pk2bf(w[0][0], w[0][1]);  p0[1] = pk2bf(w[0][2], w[0][3]);
    p0[2] = pk2bf(w[1][0], w[1][1]);  p0[3] = pk2bf(w[1][2], w[1][3]);
    p1[0] = pk2bf(w[2][0], w[2][1]);  p1[1] = pk2bf(w[2][2], w[2][3]);
    p1[2] = pk2bf(w[3][0], w[3][1]);  p1[3] = pk2bf(w[3][2], w[3][3]);
    short8 b0 = __builtin_bit_cast(short8, p0);
    short8 b1 = __builtin_bit_cast(short8, p1);
#pragma unroll
    for (int mi = 0; mi < 4; ++mi)
        acc[mi][0] = __builtin_amdgcn_mfma_f32_16x16x32_bf16(a[mi], b0, acc[mi][0], 0, 0, 0);
#pragma unroll
    for (int mi = 0; mi < 4; ++mi)
        acc[mi][1] = __builtin_amdgcn_mfma_f32_16x16x32_bf16(a[mi], b1, acc[mi][1], 0, 0, 0);
}

__global__ __launch_bounds__(256, 4)
void fc2_kernel(const u16* __restrict__ hb, const float* __restrict__ W,
                const float* __restrict__ bias, float* __restrict__ out,
                float* __restrict__ sums)
{
    int t = threadIdx.x;
    int wv = t >> 6, lane = t & 63;
    int lm = lane & 15, lk = lane >> 4;       // 0..15, 0..3
    int n0   = blockIdx.x * 32;               // block's 32 cols (W rows)
    int row0 = wv * 64;                       // wave's 64 rows

    float4_ acc[4][2];
#pragma unroll
    for (int mi = 0; mi < 4; ++mi)
#pragma unroll
        for (int ni = 0; ni < 2; ++ni)
            acc[mi][ni] = (float4_){0.f, 0.f, 0.f, 0.f};

    const u16* aptr = hb + (size_t)(row0 + lm) * FC2_K + lk * 8;
    int wr0 = n0 + lm;        if (wr0 > V_DIM - 1) wr0 = V_DIM - 1;
    int wr1 = n0 + 16 + lm;   if (wr1 > V_DIM - 1) wr1 = V_DIM - 1;
    const float* wp0 = W + (size_t)wr0 * FC2_K + lk * 8;
    const float* wp1 = W + (size_t)wr1 * FC2_K + lk * 8;

    short8  aA[4], aB[4];
    float4_ wA[4], wB[4];

    // prologue: chunk 0
#pragma unroll
    for (int mi = 0; mi < 4; ++mi)
        aA[mi] = *(const short8*)(aptr + (size_t)mi * 16 * FC2_K);
    wA[0] = *(const float4_*)(wp0);     wA[1] = *(const float4_*)(wp0 + 4);
    wA[2] = *(const float4_*)(wp1);     wA[3] = *(const float4_*)(wp1 + 4);

#pragma unroll 1
    for (int c = 0; c < 32; c += 2) {
        int kB = (c + 1) << 5;
#pragma unroll
        for (int mi = 0; mi < 4; ++mi)
            aB[mi] = *(const short8*)(aptr + (size_t)mi * 16 * FC2_K + kB);
        wB[0] = *(const float4_*)(wp0 + kB);     wB[1] = *(const float4_*)(wp0 + kB + 4);
        wB[2] = *(const float4_*)(wp1 + kB);     wB[3] = *(const float4_*)(wp1 + kB + 4);

        fc2_step(aA, wA, acc);

        if (c + 2 < 32) {
            int kA = (c + 2) << 5;
#pragma unroll
            for (int mi = 0; mi < 4; ++mi)
                aA[mi] = *(const short8*)(aptr + (size_t)mi * 16 * FC2_K + kA);
            wA[0] = *(const float4_*)(wp0 + kA);     wA[1] = *(const float4_*)(wp0 + kA + 4);
            wA[2] = *(const float4_*)(wp1 + kA);     wA[3] = *(const float4_*)(wp1 + kA + 4);
        }

        fc2_step(aB, wB, acc);
    }

    // Epilogue: e = exp(acc + bias); store; row-sum via shfl + atomic.
#pragma unroll
    for (int mi = 0; mi < 4; ++mi) {
        int r_base = row0 + mi * 16 + lk * 4;   // rows r_base..r_base+3
        float s[4] = {0.f, 0.f, 0.f, 0.f};
#pragma unroll
        for (int ni = 0; ni < 2; ++ni) {
            int col = n0 + ni * 16 + lm;
            if (col < V_DIM) {
                float bcol = bias[col];
                float4_ a = acc[mi][ni];
#pragma unroll
                for (int r = 0; r < 4; ++r) {
                    float ev = expf(a[r] + bcol);
                    out[(size_t)(r_base + r) * VP + col] = ev;
                    s[r] += ev;
                }
            }
        }
#pragma unroll
        for (int off = 1; off < 16; off <<= 1) {
#pragma unroll
            for (int r = 0; r < 4; ++r) s[r] += __shfl_xor(s[r], off);
        }
        if (lm == 0) {
#pragma unroll
            for (int r = 0; r < 4; ++r) atomicAdd(&sums[r_base + r], s[r]);
        }
    }
}

// ---------------- out = gen/sum * exp ; zero OOV tail ----------------
__global__ __launch_bounds__(256)
void rescale_kernel(float* __restrict__ out, const float* __restrict__ gen,
                    const float* __restrict__ sums)
{
    int idx = (blockIdx.x * 256 + threadIdx.x) * 2;   // total 256*50050, even
    int b = idx / VP;
    int c = idx - b * VP;
    float2 v = *(float2*)(out + idx);
    float scale = gen[b] / sums[b];
    v.x = (c     < V_DIM) ? v.x * scale : 0.f;
    v.y = (c + 1 < V_DIM) ? v.y * scale : 0.f;
    *(float2*)(out + idx) = v;
}

// ---------------- scatter: out[b, ids[b,a]] += (1-gen[b]) * att[b,a] ----------------
__global__ __launch_bounds__(256)
void scatter_kernel(const int* __restrict__ ids, const float* __restrict__ att,
                    const float* __restrict__ gen, float* __restrict__ out)
{
    int idx = blockIdx.x * 256 + threadIdx.x;   // 256*400
    int b = idx / A_DIM;
    float val = (1.f - gen[b]) * att[idx];
    atomicAdd(out + (size_t)b * VP + ids[idx], val);
}

extern "C" void kernel_launch(void* const* d_in, const int* in_sizes, int n_in,
                              void* d_out, int out_size, void* d_ws, size_t ws_size,
                              hipStream_t stream)
{
    const float* x         = (const float*)d_in[0];
    const float* enc       = (const float*)d_in[2];
    const float* enc_state = (const float*)d_in[4];
    const int*   ids       = (const int*)  d_in[6];
    const float* W_ih      = (const float*)d_in[7];
    const float* b_ih      = (const float*)d_in[9];
    const float* b_hh      = (const float*)d_in[10];
    const float* Wh_w      = (const float*)d_in[11];
    const float* Wh_b      = (const float*)d_in[12];
    const float* Ws_w      = (const float*)d_in[13];
    const float* Ws_b      = (const float*)d_in[14];
    const float* vvec      = (const float*)d_in[15];
    const float* fc1_w     = (const float*)d_in[16];
    const float* fc1_b     = (const float*)d_in[17];
    const float* fc2_w     = (const float*)d_in[18];
    const float* fc2_b     = (const float*)d_in[19];
    const float* pg1       = (const float*)d_in[20];
    const float* pg2       = (const float*)d_in[21];
    const float* pg3       = (const float*)d_in[22];
    float* out = (float*)d_out;

    float* ws    = (float*)d_ws;
    float* gates = ws;                        // 256*2048
    float* hbuf  = gates + 256 * 2048;        // 256*512
    float* ebuf  = hbuf  + 256 * 512;         // 256*400
    float* attb  = ebuf  + 256 * 400;         // 256*400
    float* dec   = attb  + 256 * 400;         // 256*912
    float* hid   = dec   + 256 * 912;         // 256*1024
    float* genb  = hid   + 256 * 1024;        // 256
    float* sums  = genb  + 256;               // 256
    u16*   hbf   = (u16*)(sums + 256);        // 256*1024 bf16

    // zero row sums (tiny; stream-ordered before fc2)
    hipMemsetAsync(sums, 0, BB * sizeof(float), stream);

    // gates = x0 @ W_ih^T + b_ih + b_hh
    sgemm<<<dim3(32, 8), 256, 0, stream>>>(x, W_ih, gates, b_ih, b_hh,
                                           BB, 2048, I_DIM, 0, 0);
    // h
    lstm_h_kernel<<<512, 256, 0, stream>>>(gates, hbuf, dec);
    // e = tanh(ES@Wh^T + Wh_b + h@Ws^T + Ws_b)
    sgemm<<<dim3(7, 8), 256, 0, stream>>>(enc_state, Wh_w, ebuf, Wh_b, nullptr,
                                          BB, A_DIM, H_DIM, 0, 0);
    sgemm<<<dim3(7, 8), 256, 0, stream>>>(hbuf, Ws_w, ebuf, Ws_b, nullptr,
                                          BB, A_DIM, H_DIM, 1, 1);
    // attention
    att_kernel<<<BB, 256, 0, stream>>>(ebuf, vvec, attb);
    // context + gen
    ctx_gen_kernel<<<BB, 512, 0, stream>>>(attb, enc, x, hbuf, pg1, pg2, pg3,
                                           dec, genb);
    // fc1
    sgemm<<<dim3(16, 8), 256, 0, stream>>>(dec, fc1_w, hid, fc1_b, nullptr,
                                           BB, FC1_OUT, FC1_IN, 0, 0);
    // hid -> bf16
    cvt_kernel<<<1024, 256, 0, stream>>>(hid, hbf);
    // fc2 + exp + row sums  (1563 = ceil(50000/32), single row-block)
    fc2_kernel<<<1563, 256, 0, stream>>>(hbf, fc2_w, fc2_b, out, sums);
    // scale by gen/sum, zero OOV tail
    rescale_kernel<<<(BB * VP) / 512, 256, 0, stream>>>(out, genb, sums);
    // pointer-copy scatter
    scatter_kernel<<<(BB * A_DIM) / 256, 256, 0, stream>>>(ids, attb, genb, out);
}